// Round 4
// baseline (347.296 us; speedup 1.0000x reference)
//
#include <hip/hip_runtime.h>

// GCN r13: rewrite layer-0 GEMM as barrier-free streaming kernel. r12 counters:
// gemm_scatter 65us @ 8% MFMA / 9% VALU / 18% HBM -> latency+barrier bound.
// W (192KB packed) is L2-resident: load B-fragments straight to registers like
// fused_gg does; no LDS, no split-K, no __syncthreads. 256 thr = 4 waves x 16
// rows, full K=512 per wave. Scatter rides along (4 edges/thr).

constexpr int NN   = 50000;
constexpr int NE   = 800000;
constexpr int KIN  = 512;
constexpr int HIDD = 96;
constexpr int ODIM = 64;
constexpr int NBLK = (NN + 255) / 256;    // 196 scan blocks
constexpr int GB   = (NN + 63) / 64;      // 782 gemm blocks
constexpr int SB   = (NE + 1023) / 1024;  // 782 scatter blocks (256 thr x 4 edges)
constexpr int HB   = (NE + 255) / 256;    // 3125 hist blocks

typedef short bf16x8 __attribute__((ext_vector_type(8)));
typedef short s8v    __attribute__((ext_vector_type(8)));
typedef float f32x4  __attribute__((ext_vector_type(4)));
typedef _Float16 h8  __attribute__((ext_vector_type(8)));

__device__ inline short f2bf(float f) {               // RTN-even fp32 -> bf16 bits
    union { float f; unsigned u; } v; v.f = f;
    unsigned r = v.u + 0x7FFFu + ((v.u >> 16) & 1u);
    return (short)(r >> 16);
}
__device__ inline short f2bf_trunc(float f) {         // truncate (for lo residual)
    union { float f; unsigned u; } v; v.f = f;
    return (short)(v.u >> 16);
}
__device__ inline float bf2f(short h) {
    union { unsigned u; float f; } v; v.u = ((unsigned)(unsigned short)h) << 16;
    return v.f;
}

// ---------------- hist (blocks [0,HB)) + weight pack (blocks [HB,HB+288)) ----
__global__ void hist_pack(const int* __restrict__ dst, int* __restrict__ deg,
                          int* __restrict__ rank,
                          const float* __restrict__ W0, const float* __restrict__ W1,
                          const float* __restrict__ W2, const float* __restrict__ FC,
                          short* __restrict__ w0hi, short* __restrict__ w0lo,
                          short* __restrict__ w1hi, short* __restrict__ w1lo,
                          short* __restrict__ w2hi, short* __restrict__ w2lo,
                          short* __restrict__ fchi, short* __restrict__ fclo) {
    if (blockIdx.x < HB) {
        const int e = blockIdx.x * 256 + threadIdx.x;
        if (e < NE) rank[e] = atomicAdd(&deg[dst[e]], 1);
        return;
    }
    const int idx = (blockIdx.x - HB) * 256 + threadIdx.x;
    const float* W; short *hi, *lo; int M, li;
    if      (idx < 49152) { W = W0; hi = w0hi; lo = w0lo; M = 96; li = idx; }
    else if (idx < 58368) { W = W1; hi = w1hi; lo = w1lo; M = 96; li = idx - 49152; }
    else if (idx < 67584) { W = W2; hi = w2hi; lo = w2lo; M = 96; li = idx - 58368; }
    else if (idx < 73728) { W = FC; hi = fchi; lo = fclo; M = 64; li = idx - 67584; }
    else return;
    const int CT = M >> 4;
    const int j = li & 7;
    const int lane = (li >> 3) & 63;
    const int t = li >> 9;             // kc*CT + ct
    const int ct = t % CT;
    const int kc = t / CT;
    const int k = kc * 32 + (lane >> 4) * 8 + j;
    const int n = ct * 16 + (lane & 15);
    const float w = W[k * M + n];
    const short h = f2bf(w);
    hi[li] = h;
    lo[li] = f2bf_trunc(w - bf2f(h));
}

// ---------------- scans ----------------
__global__ void scan1_kernel(const int* __restrict__ deg, int* __restrict__ excl,
                             int* __restrict__ partials) {
    __shared__ int tmp[256];
    const int tid = threadIdx.x;
    const int i = blockIdx.x * 256 + tid;
    const int v = (i < NN) ? deg[i] : 0;
    tmp[tid] = v;
    __syncthreads();
#pragma unroll
    for (int off = 1; off < 256; off <<= 1) {
        int t = (tid >= off) ? tmp[tid - off] : 0;
        __syncthreads();
        tmp[tid] += t;
        __syncthreads();
    }
    if (i < NN) excl[i] = tmp[tid] - v;
    if (tid == 255) partials[blockIdx.x] = tmp[tid];
}

__global__ void scan3_kernel(const int* __restrict__ excl, const int* __restrict__ partials,
                             const int* __restrict__ deg, int* __restrict__ rowstart,
                             float* __restrict__ dinv) {
    __shared__ int tmp[256];
    const int tid = threadIdx.x;
    tmp[tid] = (tid < (int)blockIdx.x) ? partials[tid] : 0;   // NBLK=196 <= 256
    __syncthreads();
#pragma unroll
    for (int off = 128; off > 0; off >>= 1) {
        if (tid < off) tmp[tid] += tmp[tid + off];
        __syncthreads();
    }
    const int boff = tmp[0];
    const int i = blockIdx.x * 256 + tid;
    if (i < NN) {
        rowstart[i] = excl[i] + boff;
        dinv[i] = 1.0f / sqrtf((float)deg[i] + 1.0f);
    }
    if (blockIdx.x == 0 && tid == 0) rowstart[NN] = NE;   // sentinel
}

// ---------------- layer-0 GEMM (blocks [0,GB)) + scatter (blocks [GB,GB+SB)) --
// Streaming GEMM: no LDS, no barriers. 4 waves x 16 rows; each wave does full
// K=512. A from HBM (2x dwordx4 per 32-col chunk), W frags from L2 (16B loads).
template <int K>   // 512
__launch_bounds__(256, 4)
__global__ void gemm_scatter(const float* __restrict__ A, const short* __restrict__ Whi,
                             const short* __restrict__ Wlo, const float* __restrict__ dinv,
                             _Float16* __restrict__ C, int N,
                             const int* __restrict__ src, const int* __restrict__ dst,
                             const int* __restrict__ rank, const int* __restrict__ rowstart,
                             int* __restrict__ csr_src) {
    constexpr int CT  = 6;
    constexpr int KCH = K / 32;        // 16 K-chunks
    const int tid = threadIdx.x;

    if (blockIdx.x >= GB) {            // ---- scatter path: 4 edges/thread ----
        const int base = (blockIdx.x - GB) * 1024 + tid;
#pragma unroll
        for (int u = 0; u < 4; ++u) {
            const int e = base + u * 256;
            if (e < NE) {
                const int d = dst[e];
                csr_src[rowstart[d] + rank[e]] = src[e];
            }
        }
        return;
    }

    const int lane = tid & 63;
    const int wave = tid >> 6;          // 0..3 row group
    const int q = lane >> 4;
    const int m = lane & 15;
    const int row = blockIdx.x * 64 + wave * 16 + m;
    const int arow = (row < N) ? row : (N - 1);

    f32x4 acc[CT];
#pragma unroll
    for (int c = 0; c < CT; ++c) acc[c] = f32x4{0.f, 0.f, 0.f, 0.f};

    const float* ap = A + (size_t)arow * K + q * 8;

#pragma unroll 4
    for (int kc = 0; kc < KCH; ++kc) {
        const float4 a0 = *(const float4*)(ap + kc * 32);
        const float4 a1 = *(const float4*)(ap + kc * 32 + 4);
        const float af[8] = {a0.x, a0.y, a0.z, a0.w, a1.x, a1.y, a1.z, a1.w};
        bf16x8 ahi, alo;
#pragma unroll
        for (int j = 0; j < 8; ++j) {
            const short h = f2bf(af[j]);
            ahi[j] = h;
            alo[j] = f2bf_trunc(af[j] - bf2f(h));
        }
        const short* hb = Whi + (size_t)kc * CT * 512 + lane * 8;
        const short* lb = Wlo + (size_t)kc * CT * 512 + lane * 8;
#pragma unroll
        for (int c = 0; c < CT; ++c) {
            const bf16x8 wh = *(const bf16x8*)(hb + c * 512);
            const bf16x8 wl = *(const bf16x8*)(lb + c * 512);
            acc[c] = __builtin_amdgcn_mfma_f32_16x16x32_bf16(ahi, wh, acc[c], 0, 0, 0);
            acc[c] = __builtin_amdgcn_mfma_f32_16x16x32_bf16(alo, wh, acc[c], 0, 0, 0);
            acc[c] = __builtin_amdgcn_mfma_f32_16x16x32_bf16(ahi, wl, acc[c], 0, 0, 0);
        }
    }

    const int rbase = blockIdx.x * 64 + wave * 16 + q * 4;
#pragma unroll
    for (int r = 0; r < 4; ++r) {
        const int orow = rbase + r;
        if (orow < N) {
            const float s = dinv[orow];
#pragma unroll
            for (int c = 0; c < CT; ++c)
                C[(size_t)orow * 96 + c * 16 + m] = (_Float16)(acc[c][r] * s);
        }
    }
}

// ---------------- fused gather + GEMM (per-node, 16B loads) ----------------
// Gather: 768 thr = 64 nodes x 12 lanes; lane owns 8 feats = ONE dwordx4/edge.
// 8-deep unroll. GEMM: 12 waves = 4 row-groups x 3 col-groups.
constexpr int APAD = 104;   // LDS row stride in shorts (208 B = 13*16 B)
template <int M, bool FC>
__launch_bounds__(768, 6)
__global__ void fused_gg(const int* __restrict__ rowstart, const float* __restrict__ dinv,
                         const int* __restrict__ csr_src, const _Float16* __restrict__ hs,
                         const float* __restrict__ gb,
                         const short* __restrict__ Whi, const short* __restrict__ Wlo,
                         const float* __restrict__ bias2,
                         _Float16* __restrict__ Ch, float* __restrict__ Cf, int N) {
    constexpr int CT = M / 16;     // 6 or 4
    __shared__ short sAhi[64 * APAD];
    __shared__ short sAlo[64 * APAD];

    const int tid = threadIdx.x;
    const int nb = blockIdx.x * 64;
    const int nl = tid / 12;            // node in tile 0..63
    const int fl = tid - nl * 12;       // feat lane 0..11, owns feats [fl*8, fl*8+8)
    const int node = nb + nl;

    s8v hi8, lo8;
    if (node < N) {
        const _Float16* __restrict__ hp = hs + fl * 8;
        float acc0[8], acc1[8];
        {
            const h8 sv = *(const h8*)(hp + (size_t)node * 96);   // self-loop
#pragma unroll
            for (int e = 0; e < 8; ++e) { acc0[e] = (float)sv[e]; acc1[e] = 0.f; }
        }
        int j = rowstart[node];
        const int jend = rowstart[node + 1];
        for (; j + 8 <= jend; j += 8) {
            const int s0 = csr_src[j],     s1 = csr_src[j + 1];
            const int s2 = csr_src[j + 2], s3 = csr_src[j + 3];
            const int s4 = csr_src[j + 4], s5 = csr_src[j + 5];
            const int s6 = csr_src[j + 6], s7 = csr_src[j + 7];
            const h8 v0 = *(const h8*)(hp + (size_t)s0 * 96);
            const h8 v1 = *(const h8*)(hp + (size_t)s1 * 96);
            const h8 v2 = *(const h8*)(hp + (size_t)s2 * 96);
            const h8 v3 = *(const h8*)(hp + (size_t)s3 * 96);
            const h8 v4 = *(const h8*)(hp + (size_t)s4 * 96);
            const h8 v5 = *(const h8*)(hp + (size_t)s5 * 96);
            const h8 v6 = *(const h8*)(hp + (size_t)s6 * 96);
            const h8 v7 = *(const h8*)(hp + (size_t)s7 * 96);
#pragma unroll
            for (int e = 0; e < 8; ++e) {
                acc0[e] += ((float)v0[e] + (float)v4[e]) + ((float)v2[e] + (float)v6[e]);
                acc1[e] += ((float)v1[e] + (float)v5[e]) + ((float)v3[e] + (float)v7[e]);
            }
        }
        if (j + 4 <= jend) {
            const int s0 = csr_src[j], s1 = csr_src[j + 1];
            const int s2 = csr_src[j + 2], s3 = csr_src[j + 3];
            const h8 v0 = *(const h8*)(hp + (size_t)s0 * 96);
            const h8 v1 = *(const h8*)(hp + (size_t)s1 * 96);
            const h8 v2 = *(const h8*)(hp + (size_t)s2 * 96);
            const h8 v3 = *(const h8*)(hp + (size_t)s3 * 96);
#pragma unroll
            for (int e = 0; e < 8; ++e) {
                acc0[e] += (float)v0[e] + (float)v2[e];
                acc1[e] += (float)v1[e] + (float)v3[e];
            }
            j += 4;
        }
        if (j + 2 <= jend) {
            const int s0 = csr_src[j], s1 = csr_src[j + 1];
            const h8 v0 = *(const h8*)(hp + (size_t)s0 * 96);
            const h8 v1 = *(const h8*)(hp + (size_t)s1 * 96);
#pragma unroll
            for (int e = 0; e < 8; ++e) {
                acc0[e] += (float)v0[e];
                acc1[e] += (float)v1[e];
            }
            j += 2;
        }
        if (j < jend) {
            const h8 v0 = *(const h8*)(hp + (size_t)csr_src[j] * 96);
#pragma unroll
            for (int e = 0; e < 8; ++e) acc0[e] += (float)v0[e];
        }
        const float di = dinv[node];
#pragma unroll
        for (int e = 0; e < 8; ++e) {
            const float o = fmaxf(fmaf(di, acc0[e] + acc1[e], gb[fl * 8 + e]), 0.0f);
            const short h = f2bf(o);
            hi8[e] = h;
            lo8[e] = f2bf_trunc(o - bf2f(h));
        }
    } else {
#pragma unroll
        for (int e = 0; e < 8; ++e) { hi8[e] = 0; lo8[e] = 0; }
    }
    *(s8v*)(sAhi + nl * APAD + fl * 8) = hi8;
    *(s8v*)(sAlo + nl * APAD + fl * 8) = lo8;
    __syncthreads();

    // ---- GEMM phase: 12 waves = 4 row groups x 3 col groups (2 tiles each) ----
    const int lane = tid & 63;
    const int wave = tid >> 6;
    const int rw = wave & 3;
    const int c0 = (wave >> 2) * 2;     // 0,2,4
    const int q = lane >> 4;
    const int m = lane & 15;

    if (c0 < CT) {
        bf16x8 Ah[3], Al[3];
#pragma unroll
        for (int kc = 0; kc < 3; ++kc) {
            const int off = (rw * 16 + m) * APAD + kc * 32 + q * 8;
            Ah[kc] = *(const bf16x8*)(sAhi + off);
            Al[kc] = *(const bf16x8*)(sAlo + off);
        }

        f32x4 gacc[2];
        gacc[0] = f32x4{0.f, 0.f, 0.f, 0.f};
        gacc[1] = f32x4{0.f, 0.f, 0.f, 0.f};

#pragma unroll
        for (int kc = 0; kc < 3; ++kc) {
#pragma unroll
            for (int c = 0; c < 2; ++c) {
                const int fo = ((kc * CT + c0 + c) * 64 + lane) * 8;
                const bf16x8 wh = *(const bf16x8*)(Whi + fo);
                const bf16x8 wl = *(const bf16x8*)(Wlo + fo);
                gacc[c] = __builtin_amdgcn_mfma_f32_16x16x32_bf16(Ah[kc], wh, gacc[c], 0, 0, 0);
                gacc[c] = __builtin_amdgcn_mfma_f32_16x16x32_bf16(Al[kc], wh, gacc[c], 0, 0, 0);
                gacc[c] = __builtin_amdgcn_mfma_f32_16x16x32_bf16(Ah[kc], wl, gacc[c], 0, 0, 0);
            }
        }

        const int rbase = nb + rw * 16 + q * 4;
#pragma unroll
        for (int r = 0; r < 4; ++r) {
            const int orow = rbase + r;
            if (orow < N) {
                if (FC) {
#pragma unroll
                    for (int c = 0; c < 2; ++c)
                        Cf[(size_t)orow * M + (c0 + c) * 16 + m] = gacc[c][r] + bias2[(c0 + c) * 16 + m];
                } else {
                    const float s = dinv[orow];
#pragma unroll
                    for (int c = 0; c < 2; ++c)
                        Ch[(size_t)orow * M + (c0 + c) * 16 + m] = (_Float16)(gacc[c][r] * s);
                }
            }
        }
    }
}

extern "C" void kernel_launch(void* const* d_in, const int* in_sizes, int n_in,
                              void* d_out, int out_size, void* d_ws, size_t ws_size,
                              hipStream_t stream) {
    const float* x   = (const float*)d_in[0];
    const int*   ei  = (const int*)d_in[1];
    const float* W0  = (const float*)d_in[2];
    const float* b0  = (const float*)d_in[3];
    const float* W1  = (const float*)d_in[4];
    const float* b1  = (const float*)d_in[5];
    const float* W2  = (const float*)d_in[6];
    const float* b2  = (const float*)d_in[7];
    const float* fcW = (const float*)d_in[8];
    const float* fcb = (const float*)d_in[9];
    float* out = (float*)d_out;

    const int* src = ei;
    const int* dst = ei + NE;

    float* ws = (float*)d_ws;
    float* dinv     = ws;                       // [50000]
    int*   deg      = (int*)(ws + 50176);
    int*   excl     = (int*)(ws + 100352);
    int*   rowstart = (int*)(ws + 200704);      // [50001] (sentinel)
    int*   partials = (int*)(ws + 250880);      // [256]
    int*   csr_src  = (int*)(ws + 251136);      // [800000]
    short* w0hi = (short*)(ws + 1051392);       // [49152] shorts
    short* w0lo = (short*)(ws + 1075968);
    short* w1hi = (short*)(ws + 1100544);       // [9216] shorts
    short* w1lo = (short*)(ws + 1105152);
    short* w2hi = (short*)(ws + 1109760);
    short* w2lo = (short*)(ws + 1114368);
    short* fchi = (short*)(ws + 1118976);       // [6144] shorts
    short* fclo = (short*)(ws + 1122048);
    _Float16* hsA = (_Float16*)(ws + 1125120);  // [4.8M halves]
    _Float16* hsB = (_Float16*)(ws + 3525120);  // [4.8M halves]
    int*   rank    = (int*)(ws + 5925120);      // [800000]

    dim3 b256(256);
    const int gHP = HB + (73728 + 255) / 256;   // 3125 + 288 = 3413
    const int gGS = GB + SB;                    // 782 + 782 = 1564
    const int gFus = GB;                        // 782 (fused, 64 nodes/blk)

    // ---- CSR build + dinv + weight pack ----
    hipMemsetAsync(deg, 0, NN * sizeof(int), stream);
    hist_pack<<<gHP, b256, 0, stream>>>(dst, deg, rank, W0, W1, W2, fcW,
                                        w0hi, w0lo, w1hi, w1lo,
                                        w2hi, w2lo, fchi, fclo);
    scan1_kernel<<<NBLK, b256, 0, stream>>>(deg, excl, partials);
    scan3_kernel<<<NBLK, b256, 0, stream>>>(excl, partials, deg, rowstart, dinv);

    // ---- layer 0 GEMM (hs0 = (x@W0)*dinv) overlapped with CSR scatter ----
    gemm_scatter<KIN><<<gGS, b256, 0, stream>>>(x, w0hi, w0lo, dinv, hsA, NN,
                                                src, dst, rank, rowstart, csr_src);

    // ---- fused: h1 = relu(gather(hs0)+b0); hs1 = (h1@W1)*dinv ----
    fused_gg<HIDD, false><<<gFus, dim3(768), 0, stream>>>(
        rowstart, dinv, csr_src, hsA, b0, w1hi, w1lo, nullptr, hsB, nullptr, NN);

    // ---- fused: h2 = relu(gather(hs1)+b1); hs2 = (h2@W2)*dinv ----
    fused_gg<HIDD, false><<<gFus, dim3(768), 0, stream>>>(
        rowstart, dinv, csr_src, hsB, b1, w2hi, w2lo, nullptr, hsA, nullptr, NN);

    // ---- fused: h3 = relu(gather(hs2)+b2); out = h3@fcW + fcb ----
    fused_gg<ODIM, true><<<gFus, dim3(768), 0, stream>>>(
        rowstart, dinv, csr_src, hsA, b2, fchi, fclo, fcb, nullptr, out, NN);
}

// Round 5
// 333.145 us; speedup vs baseline: 1.0425x; 1.0425x over previous
//
#include <hip/hip_runtime.h>

// GCN r14: gemm = r12's LDS-staged-W split-K structure + FULL A prefetch.
// r13 post-mortem: per-wave W streaming = 600MB L2 traffic + 1-deep A loads =
// latency bound (7% MFMA / 15% HBM). Fix: A strip (8 kc x 2 dwordx4) issued
// up-front into 64 VGPRs (all in flight, BW-limited), converted lazily per
// phase; W staged once per block into LDS as in r12. Scatter rides along.

constexpr int NN   = 50000;
constexpr int NE   = 800000;
constexpr int KIN  = 512;
constexpr int HIDD = 96;
constexpr int ODIM = 64;
constexpr int NBLK = (NN + 255) / 256;    // 196 scan blocks
constexpr int GB   = (NN + 63) / 64;      // 782 gemm blocks
constexpr int SB   = (NE + 511) / 512;    // 1563 scatter blocks (512 thr)
constexpr int HB   = (NE + 255) / 256;    // 3125 hist blocks

typedef short bf16x8 __attribute__((ext_vector_type(8)));
typedef short s8v    __attribute__((ext_vector_type(8)));
typedef float f32x4  __attribute__((ext_vector_type(4)));
typedef _Float16 h8  __attribute__((ext_vector_type(8)));

__device__ inline short f2bf(float f) {               // RTN-even fp32 -> bf16 bits
    union { float f; unsigned u; } v; v.f = f;
    unsigned r = v.u + 0x7FFFu + ((v.u >> 16) & 1u);
    return (short)(r >> 16);
}
__device__ inline short f2bf_trunc(float f) {         // truncate (for lo residual)
    union { float f; unsigned u; } v; v.f = f;
    return (short)(v.u >> 16);
}
__device__ inline float bf2f(short h) {
    union { unsigned u; float f; } v; v.u = ((unsigned)(unsigned short)h) << 16;
    return v.f;
}

// ---------------- hist (blocks [0,HB)) + weight pack (blocks [HB,HB+288)) ----
__global__ void hist_pack(const int* __restrict__ dst, int* __restrict__ deg,
                          int* __restrict__ rank,
                          const float* __restrict__ W0, const float* __restrict__ W1,
                          const float* __restrict__ W2, const float* __restrict__ FC,
                          short* __restrict__ w0hi, short* __restrict__ w0lo,
                          short* __restrict__ w1hi, short* __restrict__ w1lo,
                          short* __restrict__ w2hi, short* __restrict__ w2lo,
                          short* __restrict__ fchi, short* __restrict__ fclo) {
    if (blockIdx.x < HB) {
        const int e = blockIdx.x * 256 + threadIdx.x;
        if (e < NE) rank[e] = atomicAdd(&deg[dst[e]], 1);
        return;
    }
    const int idx = (blockIdx.x - HB) * 256 + threadIdx.x;
    const float* W; short *hi, *lo; int M, li;
    if      (idx < 49152) { W = W0; hi = w0hi; lo = w0lo; M = 96; li = idx; }
    else if (idx < 58368) { W = W1; hi = w1hi; lo = w1lo; M = 96; li = idx - 49152; }
    else if (idx < 67584) { W = W2; hi = w2hi; lo = w2lo; M = 96; li = idx - 58368; }
    else if (idx < 73728) { W = FC; hi = fchi; lo = fclo; M = 64; li = idx - 67584; }
    else return;
    const int CT = M >> 4;
    const int j = li & 7;
    const int lane = (li >> 3) & 63;
    const int t = li >> 9;             // kc*CT + ct
    const int ct = t % CT;
    const int kc = t / CT;
    const int k = kc * 32 + (lane >> 4) * 8 + j;
    const int n = ct * 16 + (lane & 15);
    const float w = W[k * M + n];
    const short h = f2bf(w);
    hi[li] = h;
    lo[li] = f2bf_trunc(w - bf2f(h));
}

// ---------------- scans ----------------
__global__ void scan1_kernel(const int* __restrict__ deg, int* __restrict__ excl,
                             int* __restrict__ partials) {
    __shared__ int tmp[256];
    const int tid = threadIdx.x;
    const int i = blockIdx.x * 256 + tid;
    const int v = (i < NN) ? deg[i] : 0;
    tmp[tid] = v;
    __syncthreads();
#pragma unroll
    for (int off = 1; off < 256; off <<= 1) {
        int t = (tid >= off) ? tmp[tid - off] : 0;
        __syncthreads();
        tmp[tid] += t;
        __syncthreads();
    }
    if (i < NN) excl[i] = tmp[tid] - v;
    if (tid == 255) partials[blockIdx.x] = tmp[tid];
}

__global__ void scan3_kernel(const int* __restrict__ excl, const int* __restrict__ partials,
                             const int* __restrict__ deg, int* __restrict__ rowstart,
                             float* __restrict__ dinv) {
    __shared__ int tmp[256];
    const int tid = threadIdx.x;
    tmp[tid] = (tid < (int)blockIdx.x) ? partials[tid] : 0;   // NBLK=196 <= 256
    __syncthreads();
#pragma unroll
    for (int off = 128; off > 0; off >>= 1) {
        if (tid < off) tmp[tid] += tmp[tid + off];
        __syncthreads();
    }
    const int boff = tmp[0];
    const int i = blockIdx.x * 256 + tid;
    if (i < NN) {
        rowstart[i] = excl[i] + boff;
        dinv[i] = 1.0f / sqrtf((float)deg[i] + 1.0f);
    }
    if (blockIdx.x == 0 && tid == 0) rowstart[NN] = NE;   // sentinel
}

// ---------------- layer-0 GEMM (blocks [0,GB)) + scatter (blocks [GB,GB+SB)) --
// GEMM: split-K x2, LDS-staged W (r12), A strip fully prefetched to registers.
template <int K>   // 512
__launch_bounds__(512, 4)
__global__ void gemm_scatter(const float* __restrict__ A, const short* __restrict__ Whi,
                             const short* __restrict__ Wlo, const float* __restrict__ dinv,
                             _Float16* __restrict__ C, int N,
                             const int* __restrict__ src, const int* __restrict__ dst,
                             const int* __restrict__ rank, const int* __restrict__ rowstart,
                             int* __restrict__ csr_src) {
    constexpr int CT  = 6;
    constexpr int KCH = K / 64;        // kc per half = 8
    constexpr int PH  = KCH / 2;       // 4 phases, 2 kc per half per phase
    __shared__ short sHi[4 * 3072];    // 24 KB
    __shared__ short sLo[4 * 3072];    // 24 KB

    const int tid = threadIdx.x;

    if (blockIdx.x >= GB) {            // ---- scatter path ----
        const int e = (blockIdx.x - GB) * 512 + tid;
        if (e < NE) {
            const int d = dst[e];
            csr_src[rowstart[d] + rank[e]] = src[e];
        }
        return;
    }

    const int lane = tid & 63;
    const int wave = tid >> 6;
    const int rw = wave & 3;
    const int kh = wave >> 2;
    const int q = lane >> 4;
    const int m = lane & 15;
    const int row = blockIdx.x * 64 + rw * 16 + m;
    const int arow = (row < N) ? row : (N - 1);

    f32x4 acc[CT];
#pragma unroll
    for (int c = 0; c < CT; ++c) acc[c] = f32x4{0.f, 0.f, 0.f, 0.f};

    // ---- full A-strip prefetch: 16 dwordx4, all in flight (BW-limited) ----
    const float* ap = A + (size_t)arow * K + kh * (K / 2) + q * 8;
    float4 araw[16];
#pragma unroll
    for (int t = 0; t < KCH; ++t) {
        araw[2 * t]     = *(const float4*)(ap + t * 32);
        araw[2 * t + 1] = *(const float4*)(ap + t * 32 + 4);
    }

#pragma unroll
    for (int p = 0; p < PH; ++p) {
#pragma unroll
        for (int i = 0; i < 3; ++i) {
            const int ci = i * 512 + tid;            // 0..1535
            const int slot = ci / 384;               // 384 f4 per group
            const int within = ci - slot * 384;
            const int kcg = (slot >> 1) * KCH + p * 2 + (slot & 1);
            const int so = kcg * 3072 + within * 8;
            const int doff = ci * 8;
            *(float4*)(sHi + doff) = *(const float4*)(Whi + so);
            *(float4*)(sLo + doff) = *(const float4*)(Wlo + so);
        }
        __syncthreads();

#pragma unroll
        for (int kc = 0; kc < 2; ++kc) {
            const int t = p * 2 + kc;
            const float af[8] = {araw[2 * t].x, araw[2 * t].y, araw[2 * t].z, araw[2 * t].w,
                                 araw[2 * t + 1].x, araw[2 * t + 1].y,
                                 araw[2 * t + 1].z, araw[2 * t + 1].w};
            bf16x8 ahi, alo;
#pragma unroll
            for (int j = 0; j < 8; ++j) {
                const short h = f2bf(af[j]);
                ahi[j] = h;
                alo[j] = f2bf_trunc(af[j] - bf2f(h));
            }
            const int slot = kh * 2 + kc;
            const short* hbase = sHi + slot * 3072 + lane * 8;
            const short* lbase = sLo + slot * 3072 + lane * 8;
#pragma unroll
            for (int c = 0; c < CT; ++c) {
                const bf16x8 wh = *(const bf16x8*)(hbase + c * 512);
                const bf16x8 wl = *(const bf16x8*)(lbase + c * 512);
                acc[c] = __builtin_amdgcn_mfma_f32_16x16x32_bf16(ahi, wh, acc[c], 0, 0, 0);
                acc[c] = __builtin_amdgcn_mfma_f32_16x16x32_bf16(alo, wh, acc[c], 0, 0, 0);
                acc[c] = __builtin_amdgcn_mfma_f32_16x16x32_bf16(ahi, wl, acc[c], 0, 0, 0);
            }
        }
        __syncthreads();
    }

    // split-K combine via LDS (reuse staging buffers)
    float* sAcc = (float*)sHi;
    if (kh == 1) {
#pragma unroll
        for (int c = 0; c < CT; ++c)
            *(f32x4*)(sAcc + ((rw * 64 + lane) * CT + c) * 4) = acc[c];
    }
    __syncthreads();
    if (kh == 0) {
#pragma unroll
        for (int c = 0; c < CT; ++c) {
            const f32x4 o = *(const f32x4*)(sAcc + ((rw * 64 + lane) * CT + c) * 4);
            acc[c][0] += o[0]; acc[c][1] += o[1]; acc[c][2] += o[2]; acc[c][3] += o[3];
        }
        const int rbase = blockIdx.x * 64 + rw * 16 + q * 4;
#pragma unroll
        for (int r = 0; r < 4; ++r) {
            const int orow = rbase + r;
            if (orow < N) {
                const float s = dinv[orow];
#pragma unroll
                for (int c = 0; c < CT; ++c)
                    C[(size_t)orow * 96 + c * 16 + m] = (_Float16)(acc[c][r] * s);
            }
        }
    }
}

// ---------------- fused gather + GEMM (per-node, 16B loads) ----------------
// Gather: 768 thr = 64 nodes x 12 lanes; lane owns 8 feats = ONE dwordx4/edge.
// 8-deep unroll. GEMM: 12 waves = 4 row-groups x 3 col-groups.
constexpr int APAD = 104;   // LDS row stride in shorts (208 B = 13*16 B)
template <int M, bool FC>
__launch_bounds__(768, 6)
__global__ void fused_gg(const int* __restrict__ rowstart, const float* __restrict__ dinv,
                         const int* __restrict__ csr_src, const _Float16* __restrict__ hs,
                         const float* __restrict__ gb,
                         const short* __restrict__ Whi, const short* __restrict__ Wlo,
                         const float* __restrict__ bias2,
                         _Float16* __restrict__ Ch, float* __restrict__ Cf, int N) {
    constexpr int CT = M / 16;     // 6 or 4
    __shared__ short sAhi[64 * APAD];
    __shared__ short sAlo[64 * APAD];

    const int tid = threadIdx.x;
    const int nb = blockIdx.x * 64;
    const int nl = tid / 12;            // node in tile 0..63
    const int fl = tid - nl * 12;       // feat lane 0..11, owns feats [fl*8, fl*8+8)
    const int node = nb + nl;

    s8v hi8, lo8;
    if (node < N) {
        const _Float16* __restrict__ hp = hs + fl * 8;
        float acc0[8], acc1[8];
        {
            const h8 sv = *(const h8*)(hp + (size_t)node * 96);   // self-loop
#pragma unroll
            for (int e = 0; e < 8; ++e) { acc0[e] = (float)sv[e]; acc1[e] = 0.f; }
        }
        int j = rowstart[node];
        const int jend = rowstart[node + 1];
        for (; j + 8 <= jend; j += 8) {
            const int s0 = csr_src[j],     s1 = csr_src[j + 1];
            const int s2 = csr_src[j + 2], s3 = csr_src[j + 3];
            const int s4 = csr_src[j + 4], s5 = csr_src[j + 5];
            const int s6 = csr_src[j + 6], s7 = csr_src[j + 7];
            const h8 v0 = *(const h8*)(hp + (size_t)s0 * 96);
            const h8 v1 = *(const h8*)(hp + (size_t)s1 * 96);
            const h8 v2 = *(const h8*)(hp + (size_t)s2 * 96);
            const h8 v3 = *(const h8*)(hp + (size_t)s3 * 96);
            const h8 v4 = *(const h8*)(hp + (size_t)s4 * 96);
            const h8 v5 = *(const h8*)(hp + (size_t)s5 * 96);
            const h8 v6 = *(const h8*)(hp + (size_t)s6 * 96);
            const h8 v7 = *(const h8*)(hp + (size_t)s7 * 96);
#pragma unroll
            for (int e = 0; e < 8; ++e) {
                acc0[e] += ((float)v0[e] + (float)v4[e]) + ((float)v2[e] + (float)v6[e]);
                acc1[e] += ((float)v1[e] + (float)v5[e]) + ((float)v3[e] + (float)v7[e]);
            }
        }
        if (j + 4 <= jend) {
            const int s0 = csr_src[j], s1 = csr_src[j + 1];
            const int s2 = csr_src[j + 2], s3 = csr_src[j + 3];
            const h8 v0 = *(const h8*)(hp + (size_t)s0 * 96);
            const h8 v1 = *(const h8*)(hp + (size_t)s1 * 96);
            const h8 v2 = *(const h8*)(hp + (size_t)s2 * 96);
            const h8 v3 = *(const h8*)(hp + (size_t)s3 * 96);
#pragma unroll
            for (int e = 0; e < 8; ++e) {
                acc0[e] += (float)v0[e] + (float)v2[e];
                acc1[e] += (float)v1[e] + (float)v3[e];
            }
            j += 4;
        }
        if (j + 2 <= jend) {
            const int s0 = csr_src[j], s1 = csr_src[j + 1];
            const h8 v0 = *(const h8*)(hp + (size_t)s0 * 96);
            const h8 v1 = *(const h8*)(hp + (size_t)s1 * 96);
#pragma unroll
            for (int e = 0; e < 8; ++e) {
                acc0[e] += (float)v0[e];
                acc1[e] += (float)v1[e];
            }
            j += 2;
        }
        if (j < jend) {
            const h8 v0 = *(const h8*)(hp + (size_t)csr_src[j] * 96);
#pragma unroll
            for (int e = 0; e < 8; ++e) acc0[e] += (float)v0[e];
        }
        const float di = dinv[node];
#pragma unroll
        for (int e = 0; e < 8; ++e) {
            const float o = fmaxf(fmaf(di, acc0[e] + acc1[e], gb[fl * 8 + e]), 0.0f);
            const short h = f2bf(o);
            hi8[e] = h;
            lo8[e] = f2bf_trunc(o - bf2f(h));
        }
    } else {
#pragma unroll
        for (int e = 0; e < 8; ++e) { hi8[e] = 0; lo8[e] = 0; }
    }
    *(s8v*)(sAhi + nl * APAD + fl * 8) = hi8;
    *(s8v*)(sAlo + nl * APAD + fl * 8) = lo8;
    __syncthreads();

    // ---- GEMM phase: 12 waves = 4 row groups x 3 col groups (2 tiles each) ----
    const int lane = tid & 63;
    const int wave = tid >> 6;
    const int rw = wave & 3;
    const int c0 = (wave >> 2) * 2;     // 0,2,4
    const int q = lane >> 4;
    const int m = lane & 15;

    if (c0 < CT) {
        bf16x8 Ah[3], Al[3];
#pragma unroll
        for (int kc = 0; kc < 3; ++kc) {
            const int off = (rw * 16 + m) * APAD + kc * 32 + q * 8;
            Ah[kc] = *(const bf16x8*)(sAhi + off);
            Al[kc] = *(const bf16x8*)(sAlo + off);
        }

        f32x4 gacc[2];
        gacc[0] = f32x4{0.f, 0.f, 0.f, 0.f};
        gacc[1] = f32x4{0.f, 0.f, 0.f, 0.f};

#pragma unroll
        for (int kc = 0; kc < 3; ++kc) {
#pragma unroll
            for (int c = 0; c < 2; ++c) {
                const int fo = ((kc * CT + c0 + c) * 64 + lane) * 8;
                const bf16x8 wh = *(const bf16x8*)(Whi + fo);
                const bf16x8 wl = *(const bf16x8*)(Wlo + fo);
                gacc[c] = __builtin_amdgcn_mfma_f32_16x16x32_bf16(Ah[kc], wh, gacc[c], 0, 0, 0);
                gacc[c] = __builtin_amdgcn_mfma_f32_16x16x32_bf16(Al[kc], wh, gacc[c], 0, 0, 0);
                gacc[c] = __builtin_amdgcn_mfma_f32_16x16x32_bf16(Ah[kc], wl, gacc[c], 0, 0, 0);
            }
        }

        const int rbase = nb + rw * 16 + q * 4;
#pragma unroll
        for (int r = 0; r < 4; ++r) {
            const int orow = rbase + r;
            if (orow < N) {
                if (FC) {
#pragma unroll
                    for (int c = 0; c < 2; ++c)
                        Cf[(size_t)orow * M + (c0 + c) * 16 + m] = gacc[c][r] + bias2[(c0 + c) * 16 + m];
                } else {
                    const float s = dinv[orow];
#pragma unroll
                    for (int c = 0; c < 2; ++c)
                        Ch[(size_t)orow * M + (c0 + c) * 16 + m] = (_Float16)(gacc[c][r] * s);
                }
            }
        }
    }
}

extern "C" void kernel_launch(void* const* d_in, const int* in_sizes, int n_in,
                              void* d_out, int out_size, void* d_ws, size_t ws_size,
                              hipStream_t stream) {
    const float* x   = (const float*)d_in[0];
    const int*   ei  = (const int*)d_in[1];
    const float* W0  = (const float*)d_in[2];
    const float* b0  = (const float*)d_in[3];
    const float* W1  = (const float*)d_in[4];
    const float* b1  = (const float*)d_in[5];
    const float* W2  = (const float*)d_in[6];
    const float* b2  = (const float*)d_in[7];
    const float* fcW = (const float*)d_in[8];
    const float* fcb = (const float*)d_in[9];
    float* out = (float*)d_out;

    const int* src = ei;
    const int* dst = ei + NE;

    float* ws = (float*)d_ws;
    float* dinv     = ws;                       // [50000]
    int*   deg      = (int*)(ws + 50176);
    int*   excl     = (int*)(ws + 100352);
    int*   rowstart = (int*)(ws + 200704);      // [50001] (sentinel)
    int*   partials = (int*)(ws + 250880);      // [256]
    int*   csr_src  = (int*)(ws + 251136);      // [800000]
    short* w0hi = (short*)(ws + 1051392);       // [49152] shorts
    short* w0lo = (short*)(ws + 1075968);
    short* w1hi = (short*)(ws + 1100544);       // [9216] shorts
    short* w1lo = (short*)(ws + 1105152);
    short* w2hi = (short*)(ws + 1109760);
    short* w2lo = (short*)(ws + 1114368);
    short* fchi = (short*)(ws + 1118976);       // [6144] shorts
    short* fclo = (short*)(ws + 1122048);
    _Float16* hsA = (_Float16*)(ws + 1125120);  // [4.8M halves]
    _Float16* hsB = (_Float16*)(ws + 3525120);  // [4.8M halves]
    int*   rank    = (int*)(ws + 5925120);      // [800000]

    dim3 b256(256);
    const int gHP = HB + (73728 + 255) / 256;   // 3125 + 288 = 3413
    const int gGS = GB + SB;                    // 782 + 1563 = 2345
    const int gFus = GB;                        // 782 (fused, 64 nodes/blk)

    // ---- CSR build + dinv + weight pack ----
    hipMemsetAsync(deg, 0, NN * sizeof(int), stream);
    hist_pack<<<gHP, b256, 0, stream>>>(dst, deg, rank, W0, W1, W2, fcW,
                                        w0hi, w0lo, w1hi, w1lo,
                                        w2hi, w2lo, fchi, fclo);
    scan1_kernel<<<NBLK, b256, 0, stream>>>(deg, excl, partials);
    scan3_kernel<<<NBLK, b256, 0, stream>>>(excl, partials, deg, rowstart, dinv);

    // ---- layer 0 GEMM (hs0 = (x@W0)*dinv) overlapped with CSR scatter ----
    gemm_scatter<KIN><<<gGS, dim3(512), 0, stream>>>(x, w0hi, w0lo, dinv, hsA, NN,
                                                     src, dst, rank, rowstart, csr_src);

    // ---- fused: h1 = relu(gather(hs0)+b0); hs1 = (h1@W1)*dinv ----
    fused_gg<HIDD, false><<<gFus, dim3(768), 0, stream>>>(
        rowstart, dinv, csr_src, hsA, b0, w1hi, w1lo, nullptr, hsB, nullptr, NN);

    // ---- fused: h2 = relu(gather(hs1)+b1); hs2 = (h2@W2)*dinv ----
    fused_gg<HIDD, false><<<gFus, dim3(768), 0, stream>>>(
        rowstart, dinv, csr_src, hsB, b1, w2hi, w2lo, nullptr, hsA, nullptr, NN);

    // ---- fused: h3 = relu(gather(hs2)+b2); out = h3@fcW + fcb ----
    fused_gg<ODIM, true><<<gFus, dim3(768), 0, stream>>>(
        rowstart, dinv, csr_src, hsA, b2, fchi, fclo, fcb, nullptr, out, NN);
}